// Round 1
// baseline (974.084 us; speedup 1.0000x reference)
//
#include <hip/hip_runtime.h>
#include <hip/hip_bf16.h>

// Problem constants (from reference)
constexpr int N_ = 6144;      // nodes
constexpr int E_ = 196608;    // edges per graph
constexpr int F_ = 256;       // feature dim (== H)
constexpr int D_ = 512;       // fusion dim
constexpr int G_ = 4;         // graphs
constexpr int A_ = 128;       // attention bottleneck

// ---------------------------------------------------------------------------
// Streaming: out0 = softmax(fw)[0]*Cc + [1]*Cs ; out3 = Cc ; out4 = Cs
// ---------------------------------------------------------------------------
__global__ void k_fusion(const float* __restrict__ Cc, const float* __restrict__ Cs,
                         const float* __restrict__ fw,
                         float* __restrict__ o0, float* __restrict__ o3,
                         float* __restrict__ o4)
{
    float a0 = fw[0], a1 = fw[1];
    float mx = fmaxf(a0, a1);
    float e0 = expf(a0 - mx), e1 = expf(a1 - mx);
    float w0 = e0 / (e0 + e1), w1 = e1 / (e0 + e1);
    long total = (long)N_ * N_ / 4;
    long stride = (long)gridDim.x * blockDim.x;
    for (long i = (long)blockIdx.x * blockDim.x + threadIdx.x; i < total; i += stride) {
        float4 a = ((const float4*)Cc)[i];
        float4 b = ((const float4*)Cs)[i];
        ((float4*)o3)[i] = a;
        ((float4*)o4)[i] = b;
        float4 o;
        o.x = w0 * a.x + w1 * b.x;
        o.y = w0 * a.y + w1 * b.y;
        o.z = w0 * a.z + w1 * b.z;
        o.w = w0 * a.w + w1 * b.w;
        ((float4*)o0)[i] = o;
    }
}

__global__ void k_copy(const float* __restrict__ src, float* __restrict__ dst, long n4)
{
    long i = (long)blockIdx.x * blockDim.x + threadIdx.x;
    if (i < n4) ((float4*)dst)[i] = ((const float4*)src)[i];
}

// ---------------------------------------------------------------------------
// CSR build: count -> scan -> fill
// ---------------------------------------------------------------------------
__global__ void k_count(const int* __restrict__ ei, int* __restrict__ cnt)
{
    long i = (long)blockIdx.x * blockDim.x + threadIdx.x;
    if (i >= (long)G_ * E_) return;
    int g = (int)(i / E_);
    int e = (int)(i % E_);
    int dst = ei[(long)g * 2 * E_ + E_ + e];
    atomicAdd(&cnt[g * N_ + dst], 1);
}

// one block (1024 threads) per graph; cnt_cursor holds counts on entry,
// row starts on exit. Also writes row_ptr and float deg (clamped to >=1).
__global__ void k_scan(int* __restrict__ cnt_cursor, int* __restrict__ row_ptr,
                       float* __restrict__ deg)
{
    int g = blockIdx.x;
    __shared__ int sdata[1024];
    __shared__ int s_off;
    if (threadIdx.x == 0) s_off = 0;
    __syncthreads();
    for (int base = 0; base < N_; base += 1024) {
        int idx = g * N_ + base + threadIdx.x;
        int v = cnt_cursor[idx];
        sdata[threadIdx.x] = v;
        __syncthreads();
        for (int d = 1; d < 1024; d <<= 1) {
            int t = (threadIdx.x >= d) ? sdata[threadIdx.x - d] : 0;
            __syncthreads();
            sdata[threadIdx.x] += t;
            __syncthreads();
        }
        int incl = sdata[threadIdx.x];
        int excl = incl - v;
        int rp = s_off + excl;
        row_ptr[g * (N_ + 1) + base + threadIdx.x] = rp;
        cnt_cursor[idx] = rp;
        deg[idx] = (float)(v > 1 ? v : 1);
        __syncthreads();
        if (threadIdx.x == 1023) s_off += incl;
        __syncthreads();
    }
    if (threadIdx.x == 0) row_ptr[g * (N_ + 1) + N_] = s_off;
}

__global__ void k_fill(const int* __restrict__ ei, int* __restrict__ cursor,
                       int* __restrict__ csr_src)
{
    long i = (long)blockIdx.x * blockDim.x + threadIdx.x;
    if (i >= (long)G_ * E_) return;
    int g = (int)(i / E_);
    int e = (int)(i % E_);
    int src = ei[(long)g * 2 * E_ + e];
    int dst = ei[(long)g * 2 * E_ + E_ + e];
    int pos = atomicAdd(&cursor[g * N_ + dst], 1);
    csr_src[(long)g * E_ + pos] = src;
}

// ---------------------------------------------------------------------------
// Mean aggregation: one wave per node, lane owns 4 contiguous floats (float4).
// ---------------------------------------------------------------------------
__global__ __launch_bounds__(256) void k_aggregate(
    const float* __restrict__ x, const int* __restrict__ csr_src,
    const int* __restrict__ row_ptr, const float* __restrict__ deg,
    float* __restrict__ m)
{
    int g = blockIdx.z;
    int node = blockIdx.x * 4 + (threadIdx.x >> 6);
    int lane = threadIdx.x & 63;
    const float* xg = x + (long)g * N_ * F_;
    const int* rp = row_ptr + g * (N_ + 1);
    const int* cs = csr_src + (long)g * E_;
    int s = rp[node], e = rp[node + 1];
    float4 acc = {0.f, 0.f, 0.f, 0.f};
    for (int j = s; j < e; ++j) {
        int src = cs[j];
        float4 v = *(const float4*)(xg + (long)src * F_ + lane * 4);
        acc.x += v.x; acc.y += v.y; acc.z += v.z; acc.w += v.w;
    }
    float inv = 1.0f / deg[g * N_ + node];
    acc.x *= inv; acc.y *= inv; acc.z *= inv; acc.w *= inv;
    *(float4*)(m + ((long)g * N_ + node) * F_ + lane * 4) = acc;
}

// ---------------------------------------------------------------------------
// Generic fp32 NT GEMM:  C[M,Nc] = act( A1*B1^T (+ A2*B2^T) + bias )
// A [M,K] row-major, B [Nc,K] row-major. 64x64 tile, 256 thr, 4x4 per thread.
// Batched over blockIdx.z with per-operand batch strides.
// ---------------------------------------------------------------------------
template <bool DUAL, bool RELU>
__global__ __launch_bounds__(256) void k_gemm_nt(
    const float* __restrict__ A1, const float* __restrict__ B1,
    const float* __restrict__ A2, const float* __restrict__ B2,
    const float* __restrict__ bias, float* __restrict__ C,
    int M, int Nc, int K,
    long a_batch, long b_batch, long bias_batch, long c_batch)
{
    const int g = blockIdx.z;
    A1 += (long)g * a_batch;
    B1 += (long)g * b_batch;
    const float* A2p = nullptr; const float* B2p = nullptr;
    if (DUAL) { A2p = A2 + (long)g * a_batch; B2p = B2 + (long)g * b_batch; }
    bias += (long)g * bias_batch;
    C += (long)g * c_batch;

    __shared__ float As[16][68];
    __shared__ float Bs[16][68];

    const int tid = threadIdx.x;
    const int tx = tid & 15;
    const int ty = tid >> 4;
    const int row0 = blockIdx.y * 64;
    const int col0 = blockIdx.x * 64;
    const int lr = tid >> 2;          // load row 0..63
    const int lc = (tid & 3) << 2;    // load col group 0,4,8,12

    float acc[4][4] = {};

    const int npass = DUAL ? 2 : 1;
    for (int pass = 0; pass < npass; ++pass) {
        const float* A = (DUAL && pass) ? A2p : A1;
        const float* B = (DUAL && pass) ? B2p : B1;
        for (int k0 = 0; k0 < K; k0 += 16) {
            float4 va = *(const float4*)(A + (long)(row0 + lr) * K + k0 + lc);
            float4 vb = *(const float4*)(B + (long)(col0 + lr) * K + k0 + lc);
            __syncthreads();
            As[lc + 0][lr] = va.x; As[lc + 1][lr] = va.y;
            As[lc + 2][lr] = va.z; As[lc + 3][lr] = va.w;
            Bs[lc + 0][lr] = vb.x; Bs[lc + 1][lr] = vb.y;
            Bs[lc + 2][lr] = vb.z; Bs[lc + 3][lr] = vb.w;
            __syncthreads();
            #pragma unroll
            for (int kk = 0; kk < 16; ++kk) {
                float a0 = As[kk][ty * 4 + 0], a1 = As[kk][ty * 4 + 1];
                float a2 = As[kk][ty * 4 + 2], a3 = As[kk][ty * 4 + 3];
                float b0 = Bs[kk][tx * 4 + 0], b1 = Bs[kk][tx * 4 + 1];
                float b2 = Bs[kk][tx * 4 + 2], b3 = Bs[kk][tx * 4 + 3];
                acc[0][0] += a0 * b0; acc[0][1] += a0 * b1; acc[0][2] += a0 * b2; acc[0][3] += a0 * b3;
                acc[1][0] += a1 * b0; acc[1][1] += a1 * b1; acc[1][2] += a1 * b2; acc[1][3] += a1 * b3;
                acc[2][0] += a2 * b0; acc[2][1] += a2 * b1; acc[2][2] += a2 * b2; acc[2][3] += a2 * b3;
                acc[3][0] += a3 * b0; acc[3][1] += a3 * b1; acc[3][2] += a3 * b2; acc[3][3] += a3 * b3;
            }
        }
    }
    #pragma unroll
    for (int i = 0; i < 4; ++i) {
        #pragma unroll
        for (int j = 0; j < 4; ++j) {
            float v = acc[i][j] + bias[col0 + tx * 4 + j];
            if (RELU) v = fmaxf(v, 0.f);
            C[(long)(row0 + ty * 4 + i) * Nc + col0 + tx * 4 + j] = v;
        }
    }
}

// ---------------------------------------------------------------------------
// logits[g*N+n] = sum_k h[g,n,k] * W2[k] + b2   (one wave per (g,n))
// ---------------------------------------------------------------------------
__global__ __launch_bounds__(256) void k_logits(const float* __restrict__ h,
                                                const float* __restrict__ W2,
                                                const float* __restrict__ b2,
                                                float* __restrict__ logits)
{
    int idx = blockIdx.x * 4 + (threadIdx.x >> 6);   // over G*N
    int lane = threadIdx.x & 63;
    const float* hp = h + (long)idx * A_;
    float s = hp[lane] * W2[lane] + hp[lane + 64] * W2[lane + 64];
    for (int off = 32; off > 0; off >>= 1) s += __shfl_down(s, off);
    if (lane == 0) logits[idx] = s + b2[0];
}

// ---------------------------------------------------------------------------
// out2[n,d] = relu( resid[n,d] + sum_g softmax_g(logits)[g,n] * feats[g,n,d] )
// ---------------------------------------------------------------------------
__global__ void k_fuse(const float* __restrict__ feats, const float* __restrict__ resid,
                       const float* __restrict__ logits, float* __restrict__ out2)
{
    int i = blockIdx.x * blockDim.x + threadIdx.x;   // over N*D/4
    if (i >= N_ * D_ / 4) return;
    int n = i / (D_ / 4);
    int dq = i % (D_ / 4);
    float l0 = logits[n], l1 = logits[N_ + n], l2 = logits[2 * N_ + n], l3 = logits[3 * N_ + n];
    float mx = fmaxf(fmaxf(l0, l1), fmaxf(l2, l3));
    float e0 = expf(l0 - mx), e1 = expf(l1 - mx), e2 = expf(l2 - mx), e3 = expf(l3 - mx);
    float inv = 1.f / (e0 + e1 + e2 + e3);
    e0 *= inv; e1 *= inv; e2 *= inv; e3 *= inv;
    const float4* f4 = (const float4*)feats;
    long q = (long)(D_ / 4);
    float4 q0 = f4[(long)(0 * N_ + n) * q + dq];
    float4 q1 = f4[(long)(1 * N_ + n) * q + dq];
    float4 q2 = f4[(long)(2 * N_ + n) * q + dq];
    float4 q3 = f4[(long)(3 * N_ + n) * q + dq];
    float4 r = ((const float4*)resid)[(long)n * q + dq];
    float4 o;
    o.x = fmaxf(r.x + e0 * q0.x + e1 * q1.x + e2 * q2.x + e3 * q3.x, 0.f);
    o.y = fmaxf(r.y + e0 * q0.y + e1 * q1.y + e2 * q2.y + e3 * q3.y, 0.f);
    o.z = fmaxf(r.z + e0 * q0.z + e1 * q1.z + e2 * q2.z + e3 * q3.z, 0.f);
    o.w = fmaxf(r.w + e0 * q0.w + e1 * q1.w + e2 * q2.w + e3 * q3.w, 0.f);
    ((float4*)out2)[i] = o;
}

// ---------------------------------------------------------------------------
extern "C" void kernel_launch(void* const* d_in, const int* in_sizes, int n_in,
                              void* d_out, int out_size, void* d_ws, size_t ws_size,
                              hipStream_t stream)
{
    const float* xs        = (const float*)d_in[0];
    const int*   ei        = (const int*)  d_in[1];
    const float* x_content = (const float*)d_in[2];
    const float* sage_Wl   = (const float*)d_in[3];
    const float* sage_bl   = (const float*)d_in[4];
    const float* sage_Wr   = (const float*)d_in[5];
    const float* lin_W     = (const float*)d_in[6];
    const float* lin_b     = (const float*)d_in[7];
    const float* att_W1    = (const float*)d_in[8];
    const float* att_b1    = (const float*)d_in[9];
    const float* att_W2    = (const float*)d_in[10];
    const float* att_b2    = (const float*)d_in[11];
    const float* res_W     = (const float*)d_in[12];
    const float* res_b     = (const float*)d_in[13];
    const float* fusion_w  = (const float*)d_in[14];
    const float* Cc        = (const float*)d_in[15];
    const float* Cs        = (const float*)d_in[16];

    float* out0 = (float*)d_out;                    // fusion_expression [N,N]
    float* out1 = out0 + (size_t)N_ * N_;           // x_content [N,F]
    float* out2 = out1 + (size_t)N_ * F_;           // structure_features [N,D]
    float* out3 = out2 + (size_t)N_ * D_;           // C_content [N,N]
    float* out4 = out3 + (size_t)N_ * N_;           // C_structure [N,N]

    // workspace layout
    char* w = (char*)d_ws;
    auto alloc = [&](size_t bytes) {
        char* p = w;
        w += (bytes + 255) & ~(size_t)255;
        return p;
    };
    float* xA    = (float*)alloc((size_t)G_ * N_ * F_ * 4);   // 25.2 MB
    float* xB    = (float*)alloc((size_t)G_ * N_ * F_ * 4);   // 25.2 MB
    float* mb    = (float*)alloc((size_t)G_ * N_ * F_ * 4);   // 25.2 MB
    float* feats = (float*)alloc((size_t)G_ * N_ * D_ * 4);   // 50.3 MB
    float* logit = (float*)alloc((size_t)G_ * N_ * 4);
    float* deg   = (float*)alloc((size_t)G_ * N_ * 4);
    int*   rowp  = (int*)  alloc((size_t)G_ * (N_ + 1) * 4);
    int*   curs  = (int*)  alloc((size_t)G_ * N_ * 4);
    int*   csrc  = (int*)  alloc((size_t)G_ * E_ * 4);        // 3.1 MB
    // overlays into xB (free after GNN finishes):
    float* hbuf  = xB;                                        // [G,N,128] 12.6 MB
    float* resid = (float*)((char*)xB + (size_t)G_ * N_ * A_ * 4); // [N,D] 12.6 MB

    // 1) streaming outputs (independent of everything else)
    k_fusion<<<2048, 256, 0, stream>>>(Cc, Cs, fusion_w, out0, out3, out4);
    k_copy<<<(N_ * F_ / 4 + 255) / 256, 256, 0, stream>>>(x_content, out1, (long)N_ * F_ / 4);

    // 2) CSR build
    hipMemsetAsync(curs, 0, (size_t)G_ * N_ * 4, stream);
    k_count<<<(G_ * E_ + 255) / 256, 256, 0, stream>>>(ei, curs);
    k_scan<<<G_, 1024, 0, stream>>>(curs, rowp, deg);
    k_fill<<<(G_ * E_ + 255) / 256, 256, 0, stream>>>(ei, curs, csrc);

    // 3) GNN: 3 layers, ping-pong xs -> xA -> xB -> xA
    const float* xin = xs;
    float* xout = xA;
    for (int layer = 0; layer < 3; ++layer) {
        k_aggregate<<<dim3(N_ / 4, 1, G_), 256, 0, stream>>>(xin, csrc, rowp, deg, mb);
        k_gemm_nt<true, true><<<dim3(F_ / 64, N_ / 64, G_), 256, 0, stream>>>(
            mb, sage_Wl + (size_t)layer * F_ * F_,
            xin, sage_Wr + (size_t)layer * F_ * F_,
            sage_bl + (size_t)layer * F_, xout,
            N_, F_, F_,
            (long)N_ * F_, (long)3 * F_ * F_, (long)3 * F_, (long)N_ * F_);
        xin = xout;
        xout = (layer == 0) ? xB : xA;
    }
    const float* xg = xA;  // after layer 2 result lands in xA

    // 4) feats = xg @ lin_W^T + lin_b   [G,N,D]
    k_gemm_nt<false, false><<<dim3(D_ / 64, N_ / 64, G_), 256, 0, stream>>>(
        xg, lin_W, nullptr, nullptr, lin_b, feats,
        N_, D_, F_,
        (long)N_ * F_, (long)D_ * F_, (long)D_, (long)N_ * D_);

    // 5) h = relu(feats @ att_W1^T + att_b1)   [G,N,128]
    k_gemm_nt<false, true><<<dim3(A_ / 64, N_ / 64, G_), 256, 0, stream>>>(
        feats, att_W1, nullptr, nullptr, att_b1, hbuf,
        N_, A_, D_,
        (long)N_ * D_, 0L, 0L, (long)N_ * A_);

    // 6) logits
    k_logits<<<G_ * N_ / 4, 256, 0, stream>>>(hbuf, att_W2, att_b2, logit);

    // 7) residual = feats[0] @ res_W^T + res_b   [N,D]
    k_gemm_nt<false, false><<<dim3(D_ / 64, N_ / 64, 1), 256, 0, stream>>>(
        feats, res_W, nullptr, nullptr, res_b, resid,
        N_, D_, D_,
        0L, 0L, 0L, 0L);

    // 8) out2 = relu(softmax-weighted feats + resid)
    k_fuse<<<(N_ * D_ / 4 + 255) / 256, 256, 0, stream>>>(feats, resid, logit, out2);
}

// Round 2
// 610.409 us; speedup vs baseline: 1.5958x; 1.5958x over previous
//
#include <hip/hip_runtime.h>
#include <hip/hip_bf16.h>

// Problem constants (from reference)
constexpr int N_ = 6144;      // nodes
constexpr int E_ = 196608;    // edges per graph
constexpr int F_ = 256;       // feature dim (== H)
constexpr int D_ = 512;       // fusion dim
constexpr int G_ = 4;         // graphs
constexpr int A_ = 128;       // attention bottleneck

typedef short bf16x8 __attribute__((ext_vector_type(8)));
typedef float f32x4 __attribute__((ext_vector_type(4)));

__device__ inline float b2f(unsigned short u) {
    union { unsigned u32; float f; } x; x.u32 = ((unsigned)u) << 16; return x.f;
}
__device__ inline unsigned short f2bu(float f) {
    __hip_bfloat16 b = __float2bfloat16(f);
    return *reinterpret_cast<unsigned short*>(&b);
}

#define GLD_LDS16(gp, lp) \
    __builtin_amdgcn_global_load_lds((const __attribute__((address_space(1))) void*)(gp), \
                                     (__attribute__((address_space(3))) void*)(lp), 16, 0, 0)

// ---------------------------------------------------------------------------
// Streaming: out0 = softmax(fw)[0]*Cc + [1]*Cs ; out3 = Cc ; out4 = Cs
// ---------------------------------------------------------------------------
__global__ void k_fusion(const float* __restrict__ Cc, const float* __restrict__ Cs,
                         const float* __restrict__ fw,
                         float* __restrict__ o0, float* __restrict__ o3,
                         float* __restrict__ o4)
{
    float a0 = fw[0], a1 = fw[1];
    float mx = fmaxf(a0, a1);
    float e0 = expf(a0 - mx), e1 = expf(a1 - mx);
    float w0 = e0 / (e0 + e1), w1 = e1 / (e0 + e1);
    long total = (long)N_ * N_ / 4;
    long stride = (long)gridDim.x * blockDim.x;
    for (long i = (long)blockIdx.x * blockDim.x + threadIdx.x; i < total; i += stride) {
        float4 a = ((const float4*)Cc)[i];
        float4 b = ((const float4*)Cs)[i];
        ((float4*)o3)[i] = a;
        ((float4*)o4)[i] = b;
        float4 o;
        o.x = w0 * a.x + w1 * b.x;
        o.y = w0 * a.y + w1 * b.y;
        o.z = w0 * a.z + w1 * b.z;
        o.w = w0 * a.w + w1 * b.w;
        ((float4*)o0)[i] = o;
    }
}

__global__ void k_copy(const float* __restrict__ src, float* __restrict__ dst, long n4)
{
    long i = (long)blockIdx.x * blockDim.x + threadIdx.x;
    if (i < n4) ((float4*)dst)[i] = ((const float4*)src)[i];
}

// fp32 -> bf16 conversion, 4 elements per thread
__global__ void k_f2b(const float* __restrict__ src, __hip_bfloat16* __restrict__ dst, long n4)
{
    long i = (long)blockIdx.x * blockDim.x + threadIdx.x;
    if (i >= n4) return;
    float4 v = ((const float4*)src)[i];
    ushort4 o;
    o.x = f2bu(v.x); o.y = f2bu(v.y); o.z = f2bu(v.z); o.w = f2bu(v.w);
    ((ushort4*)dst)[i] = o;
}

// ---------------------------------------------------------------------------
// CSR build: count -> scan -> fill
// ---------------------------------------------------------------------------
__global__ void k_count(const int* __restrict__ ei, int* __restrict__ cnt)
{
    long i = (long)blockIdx.x * blockDim.x + threadIdx.x;
    if (i >= (long)G_ * E_) return;
    int g = (int)(i / E_);
    int e = (int)(i % E_);
    int dst = ei[(long)g * 2 * E_ + E_ + e];
    atomicAdd(&cnt[g * N_ + dst], 1);
}

__global__ void k_scan(int* __restrict__ cnt_cursor, int* __restrict__ row_ptr,
                       float* __restrict__ deg)
{
    int g = blockIdx.x;
    __shared__ int sdata[1024];
    __shared__ int s_off;
    if (threadIdx.x == 0) s_off = 0;
    __syncthreads();
    for (int base = 0; base < N_; base += 1024) {
        int idx = g * N_ + base + threadIdx.x;
        int v = cnt_cursor[idx];
        sdata[threadIdx.x] = v;
        __syncthreads();
        for (int d = 1; d < 1024; d <<= 1) {
            int t = (threadIdx.x >= d) ? sdata[threadIdx.x - d] : 0;
            __syncthreads();
            sdata[threadIdx.x] += t;
            __syncthreads();
        }
        int incl = sdata[threadIdx.x];
        int excl = incl - v;
        int rp = s_off + excl;
        row_ptr[g * (N_ + 1) + base + threadIdx.x] = rp;
        cnt_cursor[idx] = rp;
        deg[idx] = (float)(v > 1 ? v : 1);
        __syncthreads();
        if (threadIdx.x == 1023) s_off += incl;
        __syncthreads();
    }
    if (threadIdx.x == 0) row_ptr[g * (N_ + 1) + N_] = s_off;
}

__global__ void k_fill(const int* __restrict__ ei, int* __restrict__ cursor,
                       int* __restrict__ csr_src)
{
    long i = (long)blockIdx.x * blockDim.x + threadIdx.x;
    if (i >= (long)G_ * E_) return;
    int g = (int)(i / E_);
    int e = (int)(i % E_);
    int src = ei[(long)g * 2 * E_ + e];
    int dst = ei[(long)g * 2 * E_ + E_ + e];
    int pos = atomicAdd(&cursor[g * N_ + dst], 1);
    csr_src[(long)g * E_ + pos] = src;
}

// ---------------------------------------------------------------------------
// Mean aggregation over bf16 x: one wave per node, lane owns 4 bf16 (8B).
// ---------------------------------------------------------------------------
__global__ __launch_bounds__(256) void k_aggregate(
    const __hip_bfloat16* __restrict__ x, const int* __restrict__ csr_src,
    const int* __restrict__ row_ptr, const float* __restrict__ deg,
    __hip_bfloat16* __restrict__ m)
{
    int g = blockIdx.z;
    int node = blockIdx.x * 4 + (threadIdx.x >> 6);
    int lane = threadIdx.x & 63;
    const __hip_bfloat16* xg = x + (long)g * N_ * F_;
    const int* rp = row_ptr + g * (N_ + 1);
    const int* cs = csr_src + (long)g * E_;
    int s = rp[node], e = rp[node + 1];
    float a0 = 0.f, a1 = 0.f, a2 = 0.f, a3 = 0.f;
    for (int j = s; j < e; ++j) {
        int src = cs[j];
        ushort4 v = *(const ushort4*)(xg + (long)src * F_ + lane * 4);
        a0 += b2f(v.x); a1 += b2f(v.y); a2 += b2f(v.z); a3 += b2f(v.w);
    }
    float inv = 1.0f / deg[g * N_ + node];
    ushort4 o;
    o.x = f2bu(a0 * inv); o.y = f2bu(a1 * inv); o.z = f2bu(a2 * inv); o.w = f2bu(a3 * inv);
    *(ushort4*)(m + ((long)g * N_ + node) * F_ + lane * 4) = o;
}

// ---------------------------------------------------------------------------
// bf16 MFMA NT GEMM:  C[M,Nc] = act( A1*B1^T (+ A2*B2^T) + bias )
// A [M,K] bf16 row-major, B [Nc,K] bf16 row-major, C bf16. 128x128 tile,
// 256 threads (4 waves, 2x2), BK=64, 16x16x32 MFMA, fp32 accum.
// ---------------------------------------------------------------------------
template <bool DUAL, bool RELU>
__global__ __launch_bounds__(256) void k_mfma_nt(
    const __hip_bfloat16* __restrict__ A1, const __hip_bfloat16* __restrict__ B1,
    const __hip_bfloat16* __restrict__ A2, const __hip_bfloat16* __restrict__ B2,
    const float* __restrict__ bias, __hip_bfloat16* __restrict__ C,
    int M, int Nc, int K,
    long a_batch, long b_batch, long bias_batch, long c_batch)
{
    const int g = blockIdx.z;
    const __hip_bfloat16* A1p = A1 + (long)g * a_batch;
    const __hip_bfloat16* B1p = B1 + (long)g * b_batch;
    const __hip_bfloat16* A2p = nullptr;
    const __hip_bfloat16* B2p = nullptr;
    if (DUAL) { A2p = A2 + (long)g * a_batch; B2p = B2 + (long)g * b_batch; }
    const float* biasp = bias + (long)g * bias_batch;
    __hip_bfloat16* Cp = C + (long)g * c_batch;

    __shared__ __hip_bfloat16 As[128 * 64];
    __shared__ __hip_bfloat16 Bs[128 * 64];

    const int tid = threadIdx.x;
    const int lane = tid & 63;
    const int wid = tid >> 6;
    const int wr = wid >> 1;          // wave row 0..1
    const int wc = wid & 1;           // wave col 0..1
    const int row0 = blockIdx.y * 128;
    const int col0 = blockIdx.x * 128;

    // staging coords: thread t loads 16B; chunk c covers 32 rows
    const int srow = tid >> 3;        // 0..31
    const int sk8  = (tid & 7) * 8;   // k element offset (0..56)

    f32x4 acc[4][4] = {};

    const int fr  = lane & 15;          // fragment row/col
    const int fkq = (lane >> 4) * 8;    // fragment k offset

    const int npass = DUAL ? 2 : 1;
    for (int pass = 0; pass < npass; ++pass) {
        const __hip_bfloat16* A = (DUAL && pass) ? A2p : A1p;
        const __hip_bfloat16* B = (DUAL && pass) ? B2p : B1p;
        for (int k0 = 0; k0 < K; k0 += 64) {
            __syncthreads();   // all waves done reading LDS from prev step
            #pragma unroll
            for (int c = 0; c < 4; ++c) {
                int r = c * 32 + srow;
                GLD_LDS16(A + (long)(row0 + r) * K + k0 + sk8, As + r * 64 + sk8);
                GLD_LDS16(B + (long)(col0 + r) * K + k0 + sk8, Bs + r * 64 + sk8);
            }
            __syncthreads();   // drains vmcnt: staged data visible

            bf16x8 af[4][2], bfr[4][2];
            #pragma unroll
            for (int m = 0; m < 4; ++m)
                #pragma unroll
                for (int kk = 0; kk < 2; ++kk)
                    af[m][kk] = *(const bf16x8*)(As + (wr * 64 + m * 16 + fr) * 64 + kk * 32 + fkq);
            #pragma unroll
            for (int n = 0; n < 4; ++n)
                #pragma unroll
                for (int kk = 0; kk < 2; ++kk)
                    bfr[n][kk] = *(const bf16x8*)(Bs + (wc * 64 + n * 16 + fr) * 64 + kk * 32 + fkq);

            #pragma unroll
            for (int m = 0; m < 4; ++m)
                #pragma unroll
                for (int n = 0; n < 4; ++n)
                    #pragma unroll
                    for (int kk = 0; kk < 2; ++kk)
                        acc[m][n] = __builtin_amdgcn_mfma_f32_16x16x32_bf16(
                            af[m][kk], bfr[n][kk], acc[m][n], 0, 0, 0);
        }
    }

    // epilogue: C/D layout col=lane&15, row=(lane>>4)*4+reg
    const int r4 = (lane >> 4) * 4;
    const int cc = lane & 15;
    #pragma unroll
    for (int m = 0; m < 4; ++m) {
        #pragma unroll
        for (int n = 0; n < 4; ++n) {
            int col = col0 + wc * 64 + n * 16 + cc;
            float bv = biasp[col];
            #pragma unroll
            for (int j = 0; j < 4; ++j) {
                int row = row0 + wr * 64 + m * 16 + r4 + j;
                float v = acc[m][n][j] + bv;
                if (RELU) v = fmaxf(v, 0.f);
                Cp[(long)row * Nc + col] = __float2bfloat16(v);
            }
        }
    }
}

// ---------------------------------------------------------------------------
// logits[g*N+n] = sum_k h[g,n,k] * W2[k] + b2   (one wave per (g,n))
// ---------------------------------------------------------------------------
__global__ __launch_bounds__(256) void k_logits(const __hip_bfloat16* __restrict__ h,
                                                const float* __restrict__ W2,
                                                const float* __restrict__ b2,
                                                float* __restrict__ logits)
{
    int idx = blockIdx.x * 4 + (threadIdx.x >> 6);   // over G*N
    int lane = threadIdx.x & 63;
    const __hip_bfloat16* hp = h + (long)idx * A_;
    ushort2 v = *(const ushort2*)(hp + lane * 2);
    float s = b2f(v.x) * W2[lane * 2] + b2f(v.y) * W2[lane * 2 + 1];
    for (int off = 32; off > 0; off >>= 1) s += __shfl_down(s, off);
    if (lane == 0) logits[idx] = s + b2[0];
}

// ---------------------------------------------------------------------------
// out2[n,d] = relu( resid[n,d] + sum_g softmax_g(logits)[g,n] * feats[g,n,d] )
// feats/resid bf16; 8 elements per thread.
// ---------------------------------------------------------------------------
__global__ void k_fuse(const __hip_bfloat16* __restrict__ feats,
                       const __hip_bfloat16* __restrict__ resid,
                       const float* __restrict__ logits, float* __restrict__ out2)
{
    int i = blockIdx.x * blockDim.x + threadIdx.x;   // over N*D/8
    if (i >= N_ * D_ / 8) return;
    int n = i / (D_ / 8);
    int dq = i % (D_ / 8);
    float l0 = logits[n], l1 = logits[N_ + n], l2 = logits[2 * N_ + n], l3 = logits[3 * N_ + n];
    float mx = fmaxf(fmaxf(l0, l1), fmaxf(l2, l3));
    float e0 = expf(l0 - mx), e1 = expf(l1 - mx), e2 = expf(l2 - mx), e3 = expf(l3 - mx);
    float inv = 1.f / (e0 + e1 + e2 + e3);
    e0 *= inv; e1 *= inv; e2 *= inv; e3 *= inv;

    float r[8];
    {
        ushort4 h0 = ((const ushort4*)resid)[(long)n * (D_ / 4) / 1 + dq * 2];
        ushort4 h1 = ((const ushort4*)resid)[(long)n * (D_ / 4) / 1 + dq * 2 + 1];
        r[0] = b2f(h0.x); r[1] = b2f(h0.y); r[2] = b2f(h0.z); r[3] = b2f(h0.w);
        r[4] = b2f(h1.x); r[5] = b2f(h1.y); r[6] = b2f(h1.z); r[7] = b2f(h1.w);
    }
    float wsel[4] = {e0, e1, e2, e3};
    #pragma unroll
    for (int gg = 0; gg < 4; ++gg) {
        const ushort4* fp = (const ushort4*)(feats + ((long)gg * N_ + n) * D_);
        ushort4 h0 = fp[dq * 2];
        ushort4 h1 = fp[dq * 2 + 1];
        float wv = wsel[gg];
        r[0] += wv * b2f(h0.x); r[1] += wv * b2f(h0.y);
        r[2] += wv * b2f(h0.z); r[3] += wv * b2f(h0.w);
        r[4] += wv * b2f(h1.x); r[5] += wv * b2f(h1.y);
        r[6] += wv * b2f(h1.z); r[7] += wv * b2f(h1.w);
    }
    float4 o0, o1;
    o0.x = fmaxf(r[0], 0.f); o0.y = fmaxf(r[1], 0.f);
    o0.z = fmaxf(r[2], 0.f); o0.w = fmaxf(r[3], 0.f);
    o1.x = fmaxf(r[4], 0.f); o1.y = fmaxf(r[5], 0.f);
    o1.z = fmaxf(r[6], 0.f); o1.w = fmaxf(r[7], 0.f);
    ((float4*)out2)[i * 2] = o0;
    ((float4*)out2)[i * 2 + 1] = o1;
}

// ---------------------------------------------------------------------------
extern "C" void kernel_launch(void* const* d_in, const int* in_sizes, int n_in,
                              void* d_out, int out_size, void* d_ws, size_t ws_size,
                              hipStream_t stream)
{
    const float* xs        = (const float*)d_in[0];
    const int*   ei        = (const int*)  d_in[1];
    const float* x_content = (const float*)d_in[2];
    const float* sage_Wl   = (const float*)d_in[3];
    const float* sage_bl   = (const float*)d_in[4];
    const float* sage_Wr   = (const float*)d_in[5];
    const float* lin_W     = (const float*)d_in[6];
    const float* lin_b     = (const float*)d_in[7];
    const float* att_W1    = (const float*)d_in[8];
    const float* att_b1    = (const float*)d_in[9];
    const float* att_W2    = (const float*)d_in[10];
    const float* att_b2    = (const float*)d_in[11];
    const float* res_W     = (const float*)d_in[12];
    const float* res_b     = (const float*)d_in[13];
    const float* fusion_w  = (const float*)d_in[14];
    const float* Cc        = (const float*)d_in[15];
    const float* Cs        = (const float*)d_in[16];

    float* out0 = (float*)d_out;                    // fusion_expression [N,N]
    float* out1 = out0 + (size_t)N_ * N_;           // x_content [N,F]
    float* out2 = out1 + (size_t)N_ * F_;           // structure_features [N,D]
    float* out3 = out2 + (size_t)N_ * D_;           // C_content [N,N]
    float* out4 = out3 + (size_t)N_ * N_;           // C_structure [N,N]

    // workspace layout
    char* w = (char*)d_ws;
    auto alloc = [&](size_t bytes) {
        char* p = w;
        w += (bytes + 255) & ~(size_t)255;
        return p;
    };
    typedef __hip_bfloat16 hb;
    hb* xsb   = (hb*)alloc((size_t)G_ * N_ * F_ * 2);
    hb* xA    = (hb*)alloc((size_t)G_ * N_ * F_ * 2);
    hb* xB    = (hb*)alloc((size_t)G_ * N_ * F_ * 2);
    hb* mb    = (hb*)alloc((size_t)G_ * N_ * F_ * 2);
    hb* feats = (hb*)alloc((size_t)G_ * N_ * D_ * 2);
    hb* hbuf  = (hb*)alloc((size_t)G_ * N_ * A_ * 2);
    hb* resid = (hb*)alloc((size_t)N_ * D_ * 2);
    hb* Wlb   = (hb*)alloc((size_t)G_ * 3 * F_ * F_ * 2);
    hb* Wrb   = (hb*)alloc((size_t)G_ * 3 * F_ * F_ * 2);
    hb* linWb = (hb*)alloc((size_t)G_ * D_ * F_ * 2);
    hb* attWb = (hb*)alloc((size_t)A_ * D_ * 2);
    hb* resWb = (hb*)alloc((size_t)D_ * D_ * 2);
    float* logit = (float*)alloc((size_t)G_ * N_ * 4);
    float* deg   = (float*)alloc((size_t)G_ * N_ * 4);
    int*   rowp  = (int*)  alloc((size_t)G_ * (N_ + 1) * 4);
    int*   curs  = (int*)  alloc((size_t)G_ * N_ * 4);
    int*   csrc  = (int*)  alloc((size_t)G_ * E_ * 4);

    // 1) streaming outputs (independent of everything else)
    k_fusion<<<2048, 256, 0, stream>>>(Cc, Cs, fusion_w, out0, out3, out4);
    k_copy<<<(N_ * F_ / 4 + 255) / 256, 256, 0, stream>>>(x_content, out1, (long)N_ * F_ / 4);

    // 2) conversions to bf16
    k_f2b<<<((long)G_ * N_ * F_ / 4 + 255) / 256, 256, 0, stream>>>(xs, xsb, (long)G_ * N_ * F_ / 4);
    k_f2b<<<((long)G_ * 3 * F_ * F_ / 4 + 255) / 256, 256, 0, stream>>>(sage_Wl, Wlb, (long)G_ * 3 * F_ * F_ / 4);
    k_f2b<<<((long)G_ * 3 * F_ * F_ / 4 + 255) / 256, 256, 0, stream>>>(sage_Wr, Wrb, (long)G_ * 3 * F_ * F_ / 4);
    k_f2b<<<((long)G_ * D_ * F_ / 4 + 255) / 256, 256, 0, stream>>>(lin_W, linWb, (long)G_ * D_ * F_ / 4);
    k_f2b<<<((long)A_ * D_ / 4 + 255) / 256, 256, 0, stream>>>(att_W1, attWb, (long)A_ * D_ / 4);
    k_f2b<<<((long)D_ * D_ / 4 + 255) / 256, 256, 0, stream>>>(res_W, resWb, (long)D_ * D_ / 4);

    // 3) CSR build
    hipMemsetAsync(curs, 0, (size_t)G_ * N_ * 4, stream);
    k_count<<<(G_ * E_ + 255) / 256, 256, 0, stream>>>(ei, curs);
    k_scan<<<G_, 1024, 0, stream>>>(curs, rowp, deg);
    k_fill<<<(G_ * E_ + 255) / 256, 256, 0, stream>>>(ei, curs, csrc);

    // 4) GNN: 3 layers, ping-pong xsb -> xA -> xB -> xA
    const hb* xin = xsb;
    hb* xout = xA;
    for (int layer = 0; layer < 3; ++layer) {
        k_aggregate<<<dim3(N_ / 4, 1, G_), 256, 0, stream>>>(xin, csrc, rowp, deg, mb);
        k_mfma_nt<true, true><<<dim3(F_ / 128, N_ / 128, G_), 256, 0, stream>>>(
            mb, Wlb + (size_t)layer * F_ * F_,
            xin, Wrb + (size_t)layer * F_ * F_,
            sage_bl + (size_t)layer * F_, xout,
            N_, F_, F_,
            (long)N_ * F_, (long)3 * F_ * F_, (long)3 * F_, (long)N_ * F_);
        xin = xout;
        xout = (layer == 0) ? xB : xA;
    }
    const hb* xg = xA;  // after layer 2 result lands in xA

    // 5) feats = xg @ lin_W^T + lin_b   [G,N,D] bf16
    k_mfma_nt<false, false><<<dim3(D_ / 128, N_ / 128, G_), 256, 0, stream>>>(
        xg, linWb, nullptr, nullptr, lin_b, feats,
        N_, D_, F_,
        (long)N_ * F_, (long)D_ * F_, (long)D_, (long)N_ * D_);

    // 6) h = relu(feats @ att_W1^T + att_b1)   [G,N,128] bf16
    k_mfma_nt<false, true><<<dim3(A_ / 128, N_ / 128, G_), 256, 0, stream>>>(
        feats, attWb, nullptr, nullptr, att_b1, hbuf,
        N_, A_, D_,
        (long)N_ * D_, 0L, 0L, (long)N_ * A_);

    // 7) logits
    k_logits<<<G_ * N_ / 4, 256, 0, stream>>>(hbuf, att_W2, att_b2, logit);

    // 8) residual = feats[0] @ res_W^T + res_b   [N,D] bf16
    k_mfma_nt<false, false><<<dim3(D_ / 128, N_ / 128, 1), 256, 0, stream>>>(
        feats, resWb, nullptr, nullptr, res_b, resid,
        N_, D_, D_,
        0L, 0L, 0L, 0L);

    // 9) out2 = relu(softmax-weighted feats + resid)
    k_fuse<<<(N_ * D_ / 8 + 255) / 256, 256, 0, stream>>>(feats, resid, logit, out2);
}

// Round 3
// 547.699 us; speedup vs baseline: 1.7785x; 1.1145x over previous
//
#include <hip/hip_runtime.h>
#include <hip/hip_bf16.h>

// Problem constants (from reference)
constexpr int N_ = 6144;      // nodes
constexpr int E_ = 196608;    // edges per graph
constexpr int F_ = 256;       // feature dim (== H)
constexpr int D_ = 512;       // fusion dim
constexpr int G_ = 4;         // graphs
constexpr int A_ = 128;       // attention bottleneck

typedef short bf16x8 __attribute__((ext_vector_type(8)));
typedef float f32x4 __attribute__((ext_vector_type(4)));

__device__ inline float b2f(unsigned short u) {
    union { unsigned u32; float f; } x; x.u32 = ((unsigned)u) << 16; return x.f;
}
__device__ inline unsigned short f2bu(float f) {
    __hip_bfloat16 b = __float2bfloat16(f);
    return *reinterpret_cast<unsigned short*>(&b);
}

#define GLD_LDS16(gp, lp) \
    __builtin_amdgcn_global_load_lds((const __attribute__((address_space(1))) void*)(gp), \
                                     (__attribute__((address_space(3))) void*)(lp), 16, 0, 0)

// ---------------------------------------------------------------------------
// Streaming side-work: out1 = copy(x_content); out0/3/4 = fusion of Cc/Cs.
// Disjoint [ub,ue) slices over unified index space U = N*F/4 ++ N*N/4,
// hosted by extra blocks appended to compute kernels.
// ---------------------------------------------------------------------------
struct SP {
    const float* Cc; const float* Cs; const float* fw; const float* xc;
    float* o0; float* o1; float* o3; float* o4;
    long ub; long ue; int nsb;
};

__device__ void stream_slice(const SP sp, int sb)
{
    float a0 = sp.fw[0], a1 = sp.fw[1];
    float mx = fmaxf(a0, a1);
    float e0 = expf(a0 - mx), e1 = expf(a1 - mx);
    float w0 = e0 / (e0 + e1), w1 = e1 / (e0 + e1);
    const long C4 = (long)N_ * F_ / 4;
    long stride = (long)sp.nsb * blockDim.x;
    for (long u = sp.ub + (long)sb * blockDim.x + threadIdx.x; u < sp.ue; u += stride) {
        if (u < C4) {
            ((float4*)sp.o1)[u] = ((const float4*)sp.xc)[u];
        } else {
            long i = u - C4;
            float4 a = ((const float4*)sp.Cc)[i];
            float4 b = ((const float4*)sp.Cs)[i];
            ((float4*)sp.o3)[i] = a;
            ((float4*)sp.o4)[i] = b;
            float4 o;
            o.x = w0 * a.x + w1 * b.x;
            o.y = w0 * a.y + w1 * b.y;
            o.z = w0 * a.z + w1 * b.z;
            o.w = w0 * a.w + w1 * b.w;
            ((float4*)sp.o0)[i] = o;
        }
    }
}

// fp32 -> bf16 conversion, 4 elements per thread (xs)
__global__ void k_f2b(const float* __restrict__ src, __hip_bfloat16* __restrict__ dst, long n4)
{
    long i = (long)blockIdx.x * blockDim.x + threadIdx.x;
    if (i >= n4) return;
    float4 v = ((const float4*)src)[i];
    ushort4 o;
    o.x = f2bu(v.x); o.y = f2bu(v.y); o.z = f2bu(v.z); o.w = f2bu(v.w);
    ((ushort4*)dst)[i] = o;
}

// all weight tensors in one launch; boundaries in float4 units
__global__ void k_f2b_w(const float* w0s, __hip_bfloat16* w0d, long n0,
                        const float* w1s, __hip_bfloat16* w1d, long n1,
                        const float* w2s, __hip_bfloat16* w2d, long n2,
                        const float* w3s, __hip_bfloat16* w3d, long n3,
                        const float* w4s, __hip_bfloat16* w4d, long n4)
{
    long i = (long)blockIdx.x * blockDim.x + threadIdx.x;
    const float* s; __hip_bfloat16* d; long off;
    if      (i < n0)                { s = w0s; d = w0d; off = i; }
    else if (i < n0+n1)             { s = w1s; d = w1d; off = i - n0; }
    else if (i < n0+n1+n2)          { s = w2s; d = w2d; off = i - n0 - n1; }
    else if (i < n0+n1+n2+n3)       { s = w3s; d = w3d; off = i - n0 - n1 - n2; }
    else if (i < n0+n1+n2+n3+n4)    { s = w4s; d = w4d; off = i - n0 - n1 - n2 - n3; }
    else return;
    float4 v = ((const float4*)s)[off];
    ushort4 o;
    o.x = f2bu(v.x); o.y = f2bu(v.y); o.z = f2bu(v.z); o.w = f2bu(v.w);
    ((ushort4*)d)[off] = o;
}

// ---------------------------------------------------------------------------
// CSR build: count -> scan -> fill (each hosts a streaming slice)
// ---------------------------------------------------------------------------
__global__ void k_count(const int* __restrict__ ei, int* __restrict__ cnt, SP sp)
{
    if ((int)blockIdx.x >= G_ * E_ / 256) { stream_slice(sp, blockIdx.x - G_ * E_ / 256); return; }
    long i = (long)blockIdx.x * blockDim.x + threadIdx.x;
    int g = (int)(i / E_);
    int e = (int)(i % E_);
    int dst = ei[(long)g * 2 * E_ + E_ + e];
    atomicAdd(&cnt[g * N_ + dst], 1);
}

__global__ void k_scan(int* __restrict__ cnt_cursor, int* __restrict__ row_ptr,
                       float* __restrict__ deg, SP sp)
{
    if ((int)blockIdx.x >= G_) { stream_slice(sp, blockIdx.x - G_); return; }
    int g = blockIdx.x;
    __shared__ int sdata[1024];
    __shared__ int s_off;
    if (threadIdx.x == 0) s_off = 0;
    __syncthreads();
    for (int base = 0; base < N_; base += 1024) {
        int idx = g * N_ + base + threadIdx.x;
        int v = cnt_cursor[idx];
        sdata[threadIdx.x] = v;
        __syncthreads();
        for (int d = 1; d < 1024; d <<= 1) {
            int t = (threadIdx.x >= d) ? sdata[threadIdx.x - d] : 0;
            __syncthreads();
            sdata[threadIdx.x] += t;
            __syncthreads();
        }
        int incl = sdata[threadIdx.x];
        int excl = incl - v;
        int rp = s_off + excl;
        row_ptr[g * (N_ + 1) + base + threadIdx.x] = rp;
        cnt_cursor[idx] = rp;
        deg[idx] = (float)(v > 1 ? v : 1);
        __syncthreads();
        if (threadIdx.x == 1023) s_off += incl;
        __syncthreads();
    }
    if (threadIdx.x == 0) row_ptr[g * (N_ + 1) + N_] = s_off;
}

__global__ void k_fill(const int* __restrict__ ei, int* __restrict__ cursor,
                       int* __restrict__ csr_src, SP sp)
{
    if ((int)blockIdx.x >= G_ * E_ / 256) { stream_slice(sp, blockIdx.x - G_ * E_ / 256); return; }
    long i = (long)blockIdx.x * blockDim.x + threadIdx.x;
    int g = (int)(i / E_);
    int e = (int)(i % E_);
    int src = ei[(long)g * 2 * E_ + e];
    int dst = ei[(long)g * 2 * E_ + E_ + e];
    int pos = atomicAdd(&cursor[g * N_ + dst], 1);
    csr_src[(long)g * E_ + pos] = src;
}

// ---------------------------------------------------------------------------
// Mean aggregation: one wave per node; 2 edges/iter (half-wave each, 16B/lane).
// ---------------------------------------------------------------------------
__global__ __launch_bounds__(256) void k_aggregate(
    const __hip_bfloat16* __restrict__ x, const int* __restrict__ csr_src,
    const int* __restrict__ row_ptr, const float* __restrict__ deg,
    __hip_bfloat16* __restrict__ m, SP sp)
{
    if ((int)blockIdx.x >= N_ / 4) {
        if (blockIdx.z == 0) stream_slice(sp, blockIdx.x - N_ / 4);
        return;
    }
    int g = blockIdx.z;
    int node = blockIdx.x * 4 + (threadIdx.x >> 6);
    int lane = threadIdx.x & 63;
    int half = lane >> 5;
    int l8 = (lane & 31) * 8;
    const __hip_bfloat16* xg = x + (long)g * N_ * F_;
    const int* rp = row_ptr + g * (N_ + 1);
    const int* cs = csr_src + (long)g * E_;
    int s = __builtin_amdgcn_readfirstlane(rp[node]);
    int e = __builtin_amdgcn_readfirstlane(rp[node + 1]);
    float a[8] = {};
    int j = s;
    #pragma unroll 2
    for (; j + 2 <= e; j += 2) {
        int src = cs[j + half];
        bf16x8 v = *(const bf16x8*)(xg + (long)src * F_ + l8);
        #pragma unroll
        for (int q = 0; q < 8; ++q) a[q] += b2f((unsigned short)v[q]);
    }
    if (j < e && half == 0) {
        int src = cs[j];
        bf16x8 v = *(const bf16x8*)(xg + (long)src * F_ + l8);
        #pragma unroll
        for (int q = 0; q < 8; ++q) a[q] += b2f((unsigned short)v[q]);
    }
    #pragma unroll
    for (int q = 0; q < 8; ++q) a[q] += __shfl_xor(a[q], 32);
    if (half == 0) {
        float inv = 1.0f / deg[g * N_ + node];
        bf16x8 ov;
        #pragma unroll
        for (int q = 0; q < 8; ++q) ov[q] = (short)f2bu(a[q] * inv);
        *(bf16x8*)(m + ((long)g * N_ + node) * F_ + l8) = ov;
    }
}

// ---------------------------------------------------------------------------
// bf16 MFMA NT GEMM:  C[M,Nc] = act( A1*B1^T (+ A2*B2^T) + bias )
// 128x128 tile, 256 thr (2x2 waves), BK=64, 16x16x32 MFMA, fp32 accum.
// LOGITS: instead of writing C, compute relu(h)·W2 + b2 -> logits[g*N+row].
// ---------------------------------------------------------------------------
template <bool DUAL, bool RELU, bool LOGITS>
__global__ __launch_bounds__(256) void k_mfma_nt(
    const __hip_bfloat16* __restrict__ A1, const __hip_bfloat16* __restrict__ B1,
    const __hip_bfloat16* __restrict__ A2, const __hip_bfloat16* __restrict__ B2,
    const float* __restrict__ bias, __hip_bfloat16* __restrict__ C,
    int M, int Nc, int K,
    long a_batch, long b_batch, long bias_batch, long c_batch,
    const float* __restrict__ W2, const float* __restrict__ b2,
    float* __restrict__ logits, SP sp)
{
    const int ncols = Nc >> 7;
    if ((int)blockIdx.x >= ncols) {
        if (blockIdx.z == 0)
            stream_slice(sp, (blockIdx.x - ncols) + (gridDim.x - ncols) * blockIdx.y);
        return;
    }
    const int g = blockIdx.z;
    const __hip_bfloat16* A1p = A1 + (long)g * a_batch;
    const __hip_bfloat16* B1p = B1 + (long)g * b_batch;
    const __hip_bfloat16* A2p = nullptr;
    const __hip_bfloat16* B2p = nullptr;
    if (DUAL) { A2p = A2 + (long)g * a_batch; B2p = B2 + (long)g * b_batch; }
    const float* biasp = bias + (long)g * bias_batch;
    __hip_bfloat16* Cp = C + (long)g * c_batch;

    __shared__ __hip_bfloat16 As[128 * 64];
    __shared__ __hip_bfloat16 Bs[128 * 64];
    __shared__ float sLog[2][128];

    const int tid = threadIdx.x;
    const int lane = tid & 63;
    const int wid = tid >> 6;
    const int wr = wid >> 1;
    const int wc = wid & 1;
    const int row0 = blockIdx.y * 128;
    const int col0 = blockIdx.x * 128;

    const int srow = tid >> 3;
    const int sk8  = (tid & 7) * 8;

    f32x4 acc[4][4] = {};

    const int fr  = lane & 15;
    const int fkq = (lane >> 4) * 8;

    const int npass = DUAL ? 2 : 1;
    for (int pass = 0; pass < npass; ++pass) {
        const __hip_bfloat16* A = (DUAL && pass) ? A2p : A1p;
        const __hip_bfloat16* B = (DUAL && pass) ? B2p : B1p;
        for (int k0 = 0; k0 < K; k0 += 64) {
            __syncthreads();
            #pragma unroll
            for (int c = 0; c < 4; ++c) {
                int r = c * 32 + srow;
                GLD_LDS16(A + (long)(row0 + r) * K + k0 + sk8, As + r * 64 + sk8);
                GLD_LDS16(B + (long)(col0 + r) * K + k0 + sk8, Bs + r * 64 + sk8);
            }
            __syncthreads();

            bf16x8 af[4][2], bfr[4][2];
            #pragma unroll
            for (int m = 0; m < 4; ++m)
                #pragma unroll
                for (int kk = 0; kk < 2; ++kk)
                    af[m][kk] = *(const bf16x8*)(As + (wr * 64 + m * 16 + fr) * 64 + kk * 32 + fkq);
            #pragma unroll
            for (int n = 0; n < 4; ++n)
                #pragma unroll
                for (int kk = 0; kk < 2; ++kk)
                    bfr[n][kk] = *(const bf16x8*)(Bs + (wc * 64 + n * 16 + fr) * 64 + kk * 32 + fkq);

            #pragma unroll
            for (int m = 0; m < 4; ++m)
                #pragma unroll
                for (int n = 0; n < 4; ++n)
                    #pragma unroll
                    for (int kk = 0; kk < 2; ++kk)
                        acc[m][n] = __builtin_amdgcn_mfma_f32_16x16x32_bf16(
                            af[m][kk], bfr[n][kk], acc[m][n], 0, 0, 0);
        }
    }

    const int r4 = (lane >> 4) * 4;
    const int cc = lane & 15;

    if (LOGITS) {
        // h = relu(acc + bias); logits = h . W2 + b2, reduced per row
        float w2v[4], bv[4];
        #pragma unroll
        for (int n = 0; n < 4; ++n) {
            int col = wc * 64 + n * 16 + cc;
            w2v[n] = W2[col];
            bv[n]  = biasp[col];
        }
        #pragma unroll
        for (int m = 0; m < 4; ++m) {
            #pragma unroll
            for (int j = 0; j < 4; ++j) {
                float p = 0.f;
                #pragma unroll
                for (int n = 0; n < 4; ++n) {
                    float h = fmaxf(acc[m][n][j] + bv[n], 0.f);
                    p += h * w2v[n];
                }
                p += __shfl_xor(p, 1); p += __shfl_xor(p, 2);
                p += __shfl_xor(p, 4); p += __shfl_xor(p, 8);
                if (cc == 0) sLog[wc][wr * 64 + m * 16 + r4 + j] = p;
            }
        }
        __syncthreads();
        if (tid < 128)
            logits[(long)g * N_ + row0 + tid] = sLog[0][tid] + sLog[1][tid] + b2[0];
    } else {
        #pragma unroll
        for (int m = 0; m < 4; ++m) {
            #pragma unroll
            for (int n = 0; n < 4; ++n) {
                int col = col0 + wc * 64 + n * 16 + cc;
                float bv = biasp[col];
                #pragma unroll
                for (int j = 0; j < 4; ++j) {
                    int row = row0 + wr * 64 + m * 16 + r4 + j;
                    float v = acc[m][n][j] + bv;
                    if (RELU) v = fmaxf(v, 0.f);
                    Cp[(long)row * Nc + col] = __float2bfloat16(v);
                }
            }
        }
    }
}

// ---------------------------------------------------------------------------
// out2[n,d] = relu( resid[n,d] + sum_g softmax_g(logits)[g,n] * feats[g,n,d] )
// ---------------------------------------------------------------------------
__global__ void k_fuse(const __hip_bfloat16* __restrict__ feats,
                       const __hip_bfloat16* __restrict__ resid,
                       const float* __restrict__ logits, float* __restrict__ out2)
{
    int i = blockIdx.x * blockDim.x + threadIdx.x;   // over N*D/8
    if (i >= N_ * D_ / 8) return;
    int n = i / (D_ / 8);
    int dq = i % (D_ / 8);
    float l0 = logits[n], l1 = logits[N_ + n], l2 = logits[2 * N_ + n], l3 = logits[3 * N_ + n];
    float mx = fmaxf(fmaxf(l0, l1), fmaxf(l2, l3));
    float e0 = expf(l0 - mx), e1 = expf(l1 - mx), e2 = expf(l2 - mx), e3 = expf(l3 - mx);
    float inv = 1.f / (e0 + e1 + e2 + e3);
    e0 *= inv; e1 *= inv; e2 *= inv; e3 *= inv;

    float r[8];
    {
        ushort4 h0 = ((const ushort4*)resid)[(long)n * (D_ / 4) + dq * 2];
        ushort4 h1 = ((const ushort4*)resid)[(long)n * (D_ / 4) + dq * 2 + 1];
        r[0] = b2f(h0.x); r[1] = b2f(h0.y); r[2] = b2f(h0.z); r[3] = b2f(h0.w);
        r[4] = b2f(h1.x); r[5] = b2f(h1.y); r[6] = b2f(h1.z); r[7] = b2f(h1.w);
    }
    float wsel[4] = {e0, e1, e2, e3};
    #pragma unroll
    for (int gg = 0; gg < 4; ++gg) {
        const ushort4* fp = (const ushort4*)(feats + ((long)gg * N_ + n) * D_);
        ushort4 h0 = fp[dq * 2];
        ushort4 h1 = fp[dq * 2 + 1];
        float wv = wsel[gg];
        r[0] += wv * b2f(h0.x); r[1] += wv * b2f(h0.y);
        r[2] += wv * b2f(h0.z); r[3] += wv * b2f(h0.w);
        r[4] += wv * b2f(h1.x); r[5] += wv * b2f(h1.y);
        r[6] += wv * b2f(h1.z); r[7] += wv * b2f(h1.w);
    }
    float4 o0, o1;
    o0.x = fmaxf(r[0], 0.f); o0.y = fmaxf(r[1], 0.f);
    o0.z = fmaxf(r[2], 0.f); o0.w = fmaxf(r[3], 0.f);
    o1.x = fmaxf(r[4], 0.f); o1.y = fmaxf(r[5], 0.f);
    o1.z = fmaxf(r[6], 0.f); o1.w = fmaxf(r[7], 0.f);
    ((float4*)out2)[i * 2] = o0;
    ((float4*)out2)[i * 2 + 1] = o1;
}

// ---------------------------------------------------------------------------
extern "C" void kernel_launch(void* const* d_in, const int* in_sizes, int n_in,
                              void* d_out, int out_size, void* d_ws, size_t ws_size,
                              hipStream_t stream)
{
    const float* xs        = (const float*)d_in[0];
    const int*   ei        = (const int*)  d_in[1];
    const float* x_content = (const float*)d_in[2];
    const float* sage_Wl   = (const float*)d_in[3];
    const float* sage_bl   = (const float*)d_in[4];
    const float* sage_Wr   = (const float*)d_in[5];
    const float* lin_W     = (const float*)d_in[6];
    const float* lin_b     = (const float*)d_in[7];
    const float* att_W1    = (const float*)d_in[8];
    const float* att_b1    = (const float*)d_in[9];
    const float* att_W2    = (const float*)d_in[10];
    const float* att_b2    = (const float*)d_in[11];
    const float* res_W     = (const float*)d_in[12];
    const float* res_b     = (const float*)d_in[13];
    const float* fusion_w  = (const float*)d_in[14];
    const float* Cc        = (const float*)d_in[15];
    const float* Cs        = (const float*)d_in[16];

    float* out0 = (float*)d_out;                    // fusion_expression [N,N]
    float* out1 = out0 + (size_t)N_ * N_;           // x_content [N,F]
    float* out2 = out1 + (size_t)N_ * F_;           // structure_features [N,D]
    float* out3 = out2 + (size_t)N_ * D_;           // C_content [N,N]
    float* out4 = out3 + (size_t)N_ * N_;           // C_structure [N,N]

    char* w = (char*)d_ws;
    auto alloc = [&](size_t bytes) {
        char* p = w;
        w += (bytes + 255) & ~(size_t)255;
        return p;
    };
    typedef __hip_bfloat16 hb;
    hb* xsb   = (hb*)alloc((size_t)G_ * N_ * F_ * 2);
    hb* xA    = (hb*)alloc((size_t)G_ * N_ * F_ * 2);
    hb* xB    = (hb*)alloc((size_t)G_ * N_ * F_ * 2);
    hb* mb    = (hb*)alloc((size_t)G_ * N_ * F_ * 2);
    hb* feats = (hb*)alloc((size_t)G_ * N_ * D_ * 2);
    hb* resid = (hb*)alloc((size_t)N_ * D_ * 2);
    hb* Wlb   = (hb*)alloc((size_t)G_ * 3 * F_ * F_ * 2);
    hb* Wrb   = (hb*)alloc((size_t)G_ * 3 * F_ * F_ * 2);
    hb* linWb = (hb*)alloc((size_t)G_ * D_ * F_ * 2);
    hb* attWb = (hb*)alloc((size_t)A_ * D_ * 2);
    hb* resWb = (hb*)alloc((size_t)D_ * D_ * 2);
    float* logit = (float*)alloc((size_t)G_ * N_ * 4);
    float* deg   = (float*)alloc((size_t)G_ * N_ * 4);
    int*   rowp  = (int*)  alloc((size_t)G_ * (N_ + 1) * 4);
    int*   curs  = (int*)  alloc((size_t)G_ * N_ * 4);
    int*   csrc  = (int*)  alloc((size_t)G_ * E_ * 4);

    // streaming slice boundaries over U = N*F/4 (copy) + N*N/4 (fusion)
    const long C4 = (long)N_ * F_ / 4;
    const long U  = C4 + (long)N_ * N_ / 4;
    // kernels:      count scan fill agg0 sage0 agg1 sage1 agg2 sage2 feats att resid
    const int cum[13] = {0, 5, 9, 14, 25, 34, 45, 54, 65, 74, 83, 90, 100};
    long B[13];
    for (int i = 0; i < 13; ++i) B[i] = U * cum[i] / 100;
    const int SB = 96;  // streaming blocks per hybrid kernel
    auto mkSP = [&](int i) {
        SP sp;
        sp.Cc = Cc; sp.Cs = Cs; sp.fw = fusion_w; sp.xc = x_content;
        sp.o0 = out0; sp.o1 = out1; sp.o3 = out3; sp.o4 = out4;
        sp.ub = B[i]; sp.ue = B[i + 1]; sp.nsb = SB;
        return sp;
    };

    // 1) conversions to bf16
    k_f2b<<<((long)G_ * N_ * F_ / 4 + 255) / 256, 256, 0, stream>>>(
        xs, xsb, (long)G_ * N_ * F_ / 4);
    {
        long n0 = (long)G_ * 3 * F_ * F_ / 4, n1 = n0;
        long n2 = (long)G_ * D_ * F_ / 4, n3 = (long)A_ * D_ / 4, n4 = (long)D_ * D_ / 4;
        long tot = n0 + n1 + n2 + n3 + n4;
        k_f2b_w<<<(tot + 255) / 256, 256, 0, stream>>>(
            sage_Wl, Wlb, n0, sage_Wr, Wrb, n1, lin_W, linWb, n2,
            att_W1, attWb, n3, res_W, resWb, n4);
    }

    // 2) CSR build (+ stream slices)
    hipMemsetAsync(curs, 0, (size_t)G_ * N_ * 4, stream);
    k_count<<<G_ * E_ / 256 + SB, 256, 0, stream>>>(ei, curs, mkSP(0));
    k_scan<<<G_ + SB, 1024, 0, stream>>>(curs, rowp, deg, mkSP(1));
    k_fill<<<G_ * E_ / 256 + SB, 256, 0, stream>>>(ei, curs, csrc, mkSP(2));

    // 3) GNN: 3 layers, ping-pong xsb -> xA -> xB -> xA
    const hb* xin = xsb;
    hb* xout = xA;
    for (int layer = 0; layer < 3; ++layer) {
        k_aggregate<<<dim3(N_ / 4 + SB, 1, G_), 256, 0, stream>>>(
            xin, csrc, rowp, deg, mb, mkSP(3 + 2 * layer));
        k_mfma_nt<true, true, false><<<dim3(F_ / 128 + 2, N_ / 128, G_), 256, 0, stream>>>(
            mb, Wlb + (size_t)layer * F_ * F_,
            xin, Wrb + (size_t)layer * F_ * F_,
            sage_bl + (size_t)layer * F_, xout,
            N_, F_, F_,
            (long)N_ * F_, (long)3 * F_ * F_, (long)3 * F_, (long)N_ * F_,
            nullptr, nullptr, nullptr, mkSP(4 + 2 * layer));
        xin = xout;
        xout = (layer == 0) ? xB : xA;
    }
    const hb* xg = xA;  // after layer 2 result lands in xA

    // 4) feats = xg @ lin_W^T + lin_b   [G,N,D] bf16
    k_mfma_nt<false, false, false><<<dim3(D_ / 128 + 2, N_ / 128, G_), 256, 0, stream>>>(
        xg, linWb, nullptr, nullptr, lin_b, feats,
        N_, D_, F_,
        (long)N_ * F_, (long)D_ * F_, (long)D_, (long)N_ * D_,
        nullptr, nullptr, nullptr, mkSP(9));

    // 5) logits = relu(feats @ att_W1^T + att_b1) . W2 + b2   (fused epilogue)
    k_mfma_nt<false, true, true><<<dim3(A_ / 128 + 2, N_ / 128, G_), 256, 0, stream>>>(
        feats, attWb, nullptr, nullptr, att_b1, nullptr,
        N_, A_, D_,
        (long)N_ * D_, 0L, 0L, 0L,
        att_W2, att_b2, logit, mkSP(10));

    // 6) residual = feats[0] @ res_W^T + res_b   [N,D] bf16
    k_mfma_nt<false, false, false><<<dim3(D_ / 128 + 2, N_ / 128, 1), 256, 0, stream>>>(
        feats, resWb, nullptr, nullptr, res_b, resid,
        N_, D_, D_,
        0L, 0L, 0L, 0L,
        nullptr, nullptr, nullptr, mkSP(11));

    // 7) out2 = relu(softmax-weighted feats + resid)
    k_fuse<<<(N_ * D_ / 8 + 255) / 256, 256, 0, stream>>>(feats, resid, logit, out2);
}